// Round 3
// baseline (1158.831 us; speedup 1.0000x reference)
//
#include <hip/hip_runtime.h>
#include <cmath>

typedef unsigned short u16;
typedef unsigned short u16x2 __attribute__((ext_vector_type(2)));
typedef unsigned short u16x4 __attribute__((ext_vector_type(4)));
typedef unsigned short u16x8 __attribute__((ext_vector_type(8)));
typedef short s16x8 __attribute__((ext_vector_type(8)));
typedef float f32x4 __attribute__((ext_vector_type(4)));
typedef float f32x2 __attribute__((ext_vector_type(2)));

#define B_SZ 16
#define HW 56
#define L_TOK 3136      // 56*56
#define C_DIM 512
#define NHEAD 16
#define DHEAD 32
#define WS7 7
#define NWIN 49
#define ROWS_TOTAL 50176   // 16*3136
#define MLP_DIM 2048

__device__ __forceinline__ float bf2f(u16 u) {
    union { unsigned int i; float f; } z;
    z.i = ((unsigned int)u) << 16;
    return z.f;
}
__device__ __forceinline__ u16 f2bf(float f) {
    union { float f; unsigned int i; } z;
    z.f = f;
    unsigned int r = z.i + 0x7fffu + ((z.i >> 16) & 1u);
    return (u16)(r >> 16);
}

// async global->LDS, 16B per lane; LDS dest = wave-uniform base + lane*16
__device__ __forceinline__ void gl_lds16(const u16* g, u16* l) {
    __builtin_amdgcn_global_load_lds(
        (const __attribute__((address_space(1))) unsigned int*)g,
        (__attribute__((address_space(3))) unsigned int*)l,
        16, 0, 0);
}

// ---------------------------------------------------------------------------
// 1) mod = silu(emb) @ adaLN_w + adaLN_b -> fp32 [16,3072]
// ---------------------------------------------------------------------------
__global__ __launch_bounds__(256)
void mod_kernel(const float* __restrict__ emb, const float* __restrict__ w,
                const float* __restrict__ bias, float* __restrict__ mod)
{
    int b = blockIdx.y;
    int o = blockIdx.x * 256 + threadIdx.x;
    __shared__ float se[512];
    for (int i = threadIdx.x; i < 512; i += 256) {
        float e = emb[b * 512 + i];
        se[i] = e / (1.0f + expf(-e));
    }
    __syncthreads();
    float acc = bias[o];
    #pragma unroll 8
    for (int k = 0; k < 512; ++k)
        acc += se[k] * w[(size_t)k * 3072 + o];
    mod[b * 3072 + o] = acc;
}

// ---------------------------------------------------------------------------
// 2) weight transpose + bf16 cast: Wt[n][k] = bf16(W[k][n])
// ---------------------------------------------------------------------------
__global__ __launch_bounds__(1024)
void transpose_kernel(const float* __restrict__ W, u16* __restrict__ Wt, int K, int N)
{
    __shared__ float tile[32][33];
    int k0 = blockIdx.x * 32, n0 = blockIdx.y * 32;
    tile[threadIdx.y][threadIdx.x] = W[(size_t)(k0 + threadIdx.y) * N + (n0 + threadIdx.x)];
    __syncthreads();
    Wt[(size_t)(n0 + threadIdx.y) * K + (k0 + threadIdx.x)] = f2bf(tile[threadIdx.x][threadIdx.y]);
}

// ---------------------------------------------------------------------------
// 3) LN + adaLN modulate; wave-per-row (4 rows/block), no LDS / syncthreads.
// ---------------------------------------------------------------------------
template<int WINDOWED>
__global__ __launch_bounds__(256)
void ln_kernel(const float* __restrict__ xin, const float* __restrict__ mod,
               u16* __restrict__ out, int shOff, int scOff, int rowBase)
{
    int wv   = threadIdx.x >> 6;
    int lane = threadIdx.x & 63;
    int rbl = blockIdx.x * 4 + wv;        // chunk-local row
    int rb  = rbl + rowBase;              // global sequence row
    int b = rb / L_TOK, l = rb - b * L_TOK;
    const float* xr = xin + (size_t)rb * C_DIM;
    int c0 = lane * 8;
    f32x4 u0 = *(const f32x4*)(xr + c0);
    f32x4 u1 = *(const f32x4*)(xr + c0 + 4);
    float s = u0.x + u0.y + u0.z + u0.w + u1.x + u1.y + u1.z + u1.w;
    float q = u0.x*u0.x + u0.y*u0.y + u0.z*u0.z + u0.w*u0.w
            + u1.x*u1.x + u1.y*u1.y + u1.z*u1.z + u1.w*u1.w;
    #pragma unroll
    for (int off = 32; off > 0; off >>= 1) {
        s += __shfl_xor(s, off);
        q += __shfl_xor(q, off);
    }
    float mu = s * (1.0f / 512.0f);
    float var = q * (1.0f / 512.0f) - mu * mu;
    float rstd = rsqrtf(var + 1e-6f);
    const float* mb = mod + b * 3072;
    f32x4 sc0 = *(const f32x4*)(mb + scOff + c0);
    f32x4 sc1 = *(const f32x4*)(mb + scOff + c0 + 4);
    f32x4 sh0 = *(const f32x4*)(mb + shOff + c0);
    f32x4 sh1 = *(const f32x4*)(mb + shOff + c0 + 4);
    float y[8];
    y[0] = (u0.x - mu) * rstd * (1.0f + sc0.x) + sh0.x;
    y[1] = (u0.y - mu) * rstd * (1.0f + sc0.y) + sh0.y;
    y[2] = (u0.z - mu) * rstd * (1.0f + sc0.z) + sh0.z;
    y[3] = (u0.w - mu) * rstd * (1.0f + sc0.w) + sh0.w;
    y[4] = (u1.x - mu) * rstd * (1.0f + sc1.x) + sh1.x;
    y[5] = (u1.y - mu) * rstd * (1.0f + sc1.y) + sh1.y;
    y[6] = (u1.z - mu) * rstd * (1.0f + sc1.z) + sh1.z;
    y[7] = (u1.w - mu) * rstd * (1.0f + sc1.w) + sh1.w;
    size_t drow;
    if (WINDOWED) {
        int hh = l / HW, ww = l - hh * HW;
        int hs = hh - 3; if (hs < 0) hs += HW;
        int ws2 = ww - 3; if (ws2 < 0) ws2 += HW;
        int wi = (hs / WS7) * 8 + (ws2 / WS7);
        int n  = (hs % WS7) * WS7 + (ws2 % WS7);
        int b_local = rbl / L_TOK;
        drow = (size_t)((b_local * 64 + wi) * NWIN + n);
    } else {
        drow = (size_t)rbl;
    }
    u16x8 o;
    #pragma unroll
    for (int i = 0; i < 8; ++i) o[i] = f2bf(y[i]);
    *(u16x8*)(out + drow * C_DIM + c0) = o;
}

// ---------------------------------------------------------------------------
// 4) GEMM: C[M,N] = A[M,K] @ Bt[N,K]^T + bias
//    128x128 tile, BK=32, 4 waves x (4x4) mfma_f32_16x16x32_bf16.
//    3-buffer LDS pipeline, depth-2 prefetch, counted vmcnt(4) (T3+T4):
//    stage(t+2) issued before compute(t); one raw barrier per K-step;
//    lgkmcnt(0) folded into the wait so no ds_read crosses the barrier.
//    Per-wave invariant: <=8 own gl_lds outstanding; vmcnt(4) => oldest
//    4 (tile t+1) complete. Extra loop-invariant loads hoisted by the
//    compiler are older still, so the guarantee is unaffected.
// ---------------------------------------------------------------------------
template<int EPI>
__global__ __launch_bounds__(256)
void gemm128(const u16* __restrict__ A, const u16* __restrict__ Bt,
             const float* __restrict__ bias, void* __restrict__ outv,
             const float* __restrict__ resid, const float* __restrict__ mod,
             int N, int K, int rowOffset)
{
    __shared__ u16 sA[3][128][32];   // 24 KB
    __shared__ u16 sB[3][128][32];   // 24 KB
    const int tid  = threadIdx.x;
    const int lane = tid & 63;
    const int wave = tid >> 6;
    const int wr = (wave >> 1) * 64;
    const int wc = (wave & 1) * 64;
    const int quad = lane >> 4;
    const int mrow = lane & 15;
    const int rowBase = blockIdx.x * 128;
    const int colBase = blockIdx.y * 128;

    const int r0   = wave * 32;
    const int lrow = lane >> 2;
    const int lcol = (lane & 3) * 8;          // u16 offset in row
    const u16* gA = A  + (size_t)(rowBase + r0 + lrow) * K + lcol;
    const u16* gB = Bt + (size_t)(colBase + r0 + lrow) * K + lcol;
    const size_t gstep = (size_t)16 * K;

    f32x4 acc[4][4] = {};
    const int nt = K >> 5;

#define STAGE(bi, kk) do {                                 \
    gl_lds16(gA + (kk),         &sA[bi][r0][0]);           \
    gl_lds16(gA + (kk) + gstep, &sA[bi][r0 + 16][0]);      \
    gl_lds16(gB + (kk),         &sB[bi][r0][0]);           \
    gl_lds16(gB + (kk) + gstep, &sB[bi][r0 + 16][0]);      \
} while (0)

    STAGE(0, 0);
    STAGE(1, 32);
    asm volatile("s_waitcnt vmcnt(4)" ::: "memory");   // tile 0 resident
    __builtin_amdgcn_s_barrier();

    int cur = 0, pre = 2;
    for (int t = 0; t < nt; ++t) {
        if (t + 2 < nt) STAGE(pre, (t + 2) * 32);
        s16x8 af[4], bg[4];
        #pragma unroll
        for (int tt = 0; tt < 4; ++tt) {
            af[tt] = *(const s16x8*)&sA[cur][wr + tt * 16 + mrow][quad * 8];
            bg[tt] = *(const s16x8*)&sB[cur][wc + tt * 16 + mrow][quad * 8];
        }
        #pragma unroll
        for (int tm = 0; tm < 4; ++tm)
            #pragma unroll
            for (int tn = 0; tn < 4; ++tn)
                acc[tm][tn] = __builtin_amdgcn_mfma_f32_16x16x32_bf16(
                    af[tm], bg[tn], acc[tm][tn], 0, 0, 0);
        if (t + 1 < nt) {
            if (t + 2 < nt)
                asm volatile("s_waitcnt vmcnt(4) lgkmcnt(0)" ::: "memory");
            else
                asm volatile("s_waitcnt vmcnt(0) lgkmcnt(0)" ::: "memory");
            __builtin_amdgcn_s_barrier();
        }
        cur = (cur == 2) ? 0 : cur + 1;
        pre = (pre == 2) ? 0 : pre + 1;
    }
#undef STAGE

    #pragma unroll
    for (int tm = 0; tm < 4; ++tm) {
        #pragma unroll
        for (int tn = 0; tn < 4; ++tn) {
            int col = colBase + wc + tn * 16 + mrow;
            float bv = bias[col];
            #pragma unroll
            for (int i = 0; i < 4; ++i) {
                int r = rowBase + wr + tm * 16 + quad * 4 + i;   // chunk-local
                float v = acc[tm][tn][i] + bv;
                if constexpr (EPI == 0) {
                    ((u16*)outv)[(size_t)r * N + col] = f2bf(v);
                } else if constexpr (EPI == 1) {
                    float g = 0.5f * v * (1.0f + erff(v * 0.70710678118654752f));
                    ((u16*)outv)[(size_t)r * N + col] = f2bf(g);
                } else if constexpr (EPI == 2) {
                    int rg = r + rowOffset;        // global window-layout row
                    int b = rg / L_TOK;
                    int rem = rg - b * L_TOK;
                    int wi = rem / NWIN;
                    int n  = rem - wi * NWIN;
                    int hs  = (wi >> 3) * WS7 + n / WS7;
                    int ws2 = (wi & 7) * WS7 + n % WS7;
                    int hh = hs + 3;  if (hh >= HW)  hh -= HW;
                    int ww = ws2 + 3; if (ww >= HW)  ww -= HW;
                    size_t dst = ((size_t)(b * L_TOK + hh * HW + ww)) * C_DIM + col;
                    float g = mod[b * 3072 + 1024 + col];
                    ((float*)outv)[dst] = resid[dst] + g * v;
                } else {  // EPI == 3
                    int rg = r + rowOffset;        // global sequence row
                    int b = rg / L_TOK;
                    size_t dst = (size_t)rg * C_DIM + col;
                    float g = mod[b * 3072 + 2560 + col];
                    ((float*)outv)[dst] = resid[dst] + g * v;
                }
            }
        }
    }
}

// ---------------------------------------------------------------------------
// 5) MFMA windowed attention. Block = 4 waves = 4 heads of one window.
// ---------------------------------------------------------------------------
__global__ __launch_bounds__(256)
void attn_mfma(const u16* __restrict__ qkv, const float* __restrict__ bias_table,
               u16* __restrict__ out)
{
    const int w    = blockIdx.x;          // chunk-local: b_local*64 + wi
    const int hg   = blockIdx.y;          // 0..3
    const int wave = threadIdx.x >> 6;
    const int lane = threadIdx.x & 63;
    const int h    = hg * 4 + wave;
    const int wi   = w & 63;
    const int quad = lane >> 4;
    const int mrow = lane & 15;

    __shared__ u16 sP[4][64][72];      // per-wave P (bf16), pitch 72 (144B rows)
    __shared__ u16 sVt[4][32][72];     // per-wave V^T (bf16)
    __shared__ float sBias[4][169];    // per-wave head bias slice

    const u16* qb = qkv + (size_t)w * NWIN * 1536 + h * DHEAD;

    // stage per-head bias slice (strided global, L2-resident table)
    for (int e = lane; e < 169; e += 64)
        sBias[wave][e] = bias_table[e * NHEAD + h];

    // stage V transposed: rows 0..48 real, 49..63 zeroed
    #pragma unroll
    for (int rr = 0; rr < 4; ++rr) {
        int e = rr * 64 + lane;
        int r = e >> 2, d0 = (e & 3) * 8;
        u16x8 vv = {};
        if (e < 196)
            vv = *(const u16x8*)(qb + (size_t)r * 1536 + 1024 + d0);
        #pragma unroll
        for (int j = 0; j < 8; ++j)
            sVt[wave][d0 + j][r] = vv[j];
    }

    // Q/K fragments direct from global; pad rows (49..63) clamped to 48
    s16x8 qf[4], kf[4];
    #pragma unroll
    for (int t = 0; t < 4; ++t) {
        int r = t * 16 + mrow; if (r > 48) r = 48;
        qf[t] = *(const s16x8*)(qb + (size_t)r * 1536 + quad * 8);
        kf[t] = *(const s16x8*)(qb + (size_t)r * 1536 + 512 + quad * 8);
    }
    __syncthreads();   // sVt / sBias visible

    // S = Q K^T : S[m][n], m = tm*16+quad*4+i, n = tn*16+mrow
    f32x4 sacc[4][4] = {};
    #pragma unroll
    for (int tm = 0; tm < 4; ++tm)
        #pragma unroll
        for (int tn = 0; tn < 4; ++tn)
            sacc[tm][tn] = __builtin_amdgcn_mfma_f32_16x16x32_bf16(
                qf[tm], kf[tn], sacc[tm][tn], 0, 0, 0);

    const float scale = 0.17677669529663687f;   // 1/sqrt(32)
    const int wh = wi >> 3, ww = wi & 7;

    // per-lane key-side terms (constant across tm,i)
    int khA[4], kwA[4], rkA[4], nOK[4];
    #pragma unroll
    for (int tn = 0; tn < 4; ++tn) {
        int n = tn * 16 + mrow;
        nOK[tn] = (n < NWIN);
        int nc = n > 48 ? 48 : n;
        khA[tn] = nc / 7; kwA[tn] = nc - khA[tn] * 7;
        int gkh = wh * 7 + khA[tn], gkw = ww * 7 + kwA[tn];
        rkA[tn] = (gkh < 49 ? 0 : (gkh < 53 ? 1 : 2)) * 3
                + (gkw < 49 ? 0 : (gkw < 53 ? 1 : 2));
    }

    #pragma unroll
    for (int tm = 0; tm < 4; ++tm) {
        #pragma unroll
        for (int i = 0; i < 4; ++i) {
            int m = tm * 16 + quad * 4 + i;
            int mc = m > 48 ? 48 : m;            // garbage rows: keep idx bounded
            int qh = mc / 7, qw = mc - qh * 7;
            int gqh = wh * 7 + qh, gqw = ww * 7 + qw;
            int rq = (gqh < 49 ? 0 : (gqh < 53 ? 1 : 2)) * 3
                   + (gqw < 49 ? 0 : (gqw < 53 ? 1 : 2));
            float v[4];
            #pragma unroll
            for (int tn = 0; tn < 4; ++tn) {
                float s = sacc[tm][tn][i] * scale;
                s += sBias[wave][(qh - khA[tn] + 6) * 13 + (qw - kwA[tn] + 6)];
                if (rq != rkA[tn]) s -= 100.0f;
                v[tn] = nOK[tn] ? s : -1e30f;
            }
            float mx = fmaxf(fmaxf(v[0], v[1]), fmaxf(v[2], v[3]));
            mx = fmaxf(mx, __shfl_xor(mx, 1));
            mx = fmaxf(mx, __shfl_xor(mx, 2));
            mx = fmaxf(mx, __shfl_xor(mx, 4));
            mx = fmaxf(mx, __shfl_xor(mx, 8));
            float p0 = __expf(v[0] - mx), p1 = __expf(v[1] - mx);
            float p2 = __expf(v[2] - mx), p3 = __expf(v[3] - mx);
            float sum = p0 + p1 + p2 + p3;
            sum += __shfl_xor(sum, 1);
            sum += __shfl_xor(sum, 2);
            sum += __shfl_xor(sum, 4);
            sum += __shfl_xor(sum, 8);
            float inv = 1.0f / sum;
            float pp[4] = { p0 * inv, p1 * inv, p2 * inv, p3 * inv };
            // pack (n, n+1) bf16 pairs via neighbor shfl; even-mrow lanes write
            #pragma unroll
            for (int tn = 0; tn < 4; ++tn) {
                float po = __shfl_xor(pp[tn], 1);
                if (!(mrow & 1)) {
                    unsigned int pk = (unsigned int)f2bf(pp[tn])
                                    | ((unsigned int)f2bf(po) << 16);
                    *(unsigned int*)&sP[wave][m][tn * 16 + mrow] = pk;
                }
            }
        }
    }
    __syncthreads();   // sP ready

    // O^T[d][m] = sum_n V[n][d] * P[m][n] ; A = V^T frags, B = P frags
    f32x4 oacc[2][4] = {};
    #pragma unroll
    for (int ks = 0; ks < 2; ++ks) {
        s16x8 vf[2], pf[4];
        #pragma unroll
        for (int td = 0; td < 2; ++td)
            vf[td] = *(const s16x8*)&sVt[wave][td * 16 + mrow][ks * 32 + quad * 8];
        #pragma unroll
        for (int tm = 0; tm < 4; ++tm)
            pf[tm] = *(const s16x8*)&sP[wave][tm * 16 + mrow][ks * 32 + quad * 8];
        #pragma unroll
        for (int td = 0; td < 2; ++td)
            #pragma unroll
            for (int tm = 0; tm < 4; ++tm)
                oacc[td][tm] = __builtin_amdgcn_mfma_f32_16x16x32_bf16(
                    vf[td], pf[tm], oacc[td][tm], 0, 0, 0);
    }

    // store: lane holds O^T[d = td*16+quad*4+i][m = tm*16+mrow]
    #pragma unroll
    for (int tm = 0; tm < 4; ++tm) {
        int m = tm * 16 + mrow;
        if (m < NWIN) {
            u16* orow = out + ((size_t)(w * NWIN + m)) * C_DIM + h * DHEAD;
            #pragma unroll
            for (int td = 0; td < 2; ++td) {
                u16x4 ov;
                #pragma unroll
                for (int i = 0; i < 4; ++i) ov[i] = f2bf(oacc[td][tm][i]);
                *(u16x4*)(orow + td * 16 + quad * 4) = ov;
            }
        }
    }
}

// ---------------------------------------------------------------------------
// fp32 I/O, bf16 compute core. x2 lives in d_out.
// Workspace: two aliased slots (lifetimes disjoint):
//   slotS = winC -> aoC -> h2C   (CB * 3136 * 512  * 2B per batch)
//   slotL = qkvC -> ffiC         (CB * 3136 * 2048 * 2B per batch)
// CB=4 totals exactly 70,713,344 B == the previously-proven footprint.
// ---------------------------------------------------------------------------
extern "C" void kernel_launch(void* const* d_in, const int* in_sizes, int n_in,
                              void* d_out, int out_size, void* d_ws, size_t ws_size,
                              hipStream_t stream)
{
    const float* x       = (const float*)d_in[0];
    const float* emb     = (const float*)d_in[1];
    const float* adaLN_w = (const float*)d_in[2];
    const float* adaLN_b = (const float*)d_in[3];
    const float* qkv_w   = (const float*)d_in[4];
    const float* qkv_b   = (const float*)d_in[5];
    const float* proj_w  = (const float*)d_in[6];
    const float* proj_b  = (const float*)d_in[7];
    const float* relb    = (const float*)d_in[8];
    const float* ff_w1   = (const float*)d_in[9];
    const float* ff_b1   = (const float*)d_in[10];
    const float* ff_w2   = (const float*)d_in[11];
    const float* ff_b2   = (const float*)d_in[12];
    float* outp = (float*)d_out;

    char* ws = (char*)d_ws;
    float* mod   = (float*)(ws + 0);                  //    196,608 B
    u16* wT_qkv  = (u16*)(ws + 196608);               //  1,572,864 B
    u16* wT_proj = (u16*)(ws + 1769472);              //    524,288 B
    u16* wT_ff1  = (u16*)(ws + 2293760);              //  2,097,152 B
    u16* wT_ff2  = (u16*)(ws + 4390912);              //  2,097,152 B
    char* slots  = ws + 6488064;

    const size_t perB_S = (size_t)L_TOK * C_DIM * sizeof(u16);   //  3,211,264
    const size_t perB_L = (size_t)L_TOK * MLP_DIM * sizeof(u16); // 12,845,056

    int CB = 4;   // 6,488,064 + 4*(perB_S+perB_L) == 70,713,344 (proven fit)
    if (ws_size >= 6488064 + 8 * (perB_S + perB_L)) CB = 8;

    const int nChunks   = B_SZ / CB;
    const int chunkRows = CB * L_TOK;
    u16* slotS = (u16*)slots;                         // winC / aoC / h2C
    u16* slotL = (u16*)(slots + (size_t)CB * perB_S); // qkvC / ffiC

    // prolog (once)
    mod_kernel<<<dim3(12, 16), dim3(256), 0, stream>>>(emb, adaLN_w, adaLN_b, mod);
    transpose_kernel<<<dim3(16, 48), dim3(32, 32), 0, stream>>>(qkv_w,  wT_qkv, 512, 1536);
    transpose_kernel<<<dim3(16, 16), dim3(32, 32), 0, stream>>>(proj_w, wT_proj, 512, 512);
    transpose_kernel<<<dim3(16, 64), dim3(32, 32), 0, stream>>>(ff_w1,  wT_ff1, 512, 2048);
    transpose_kernel<<<dim3(64, 16), dim3(32, 32), 0, stream>>>(ff_w2,  wT_ff2, 2048, 512);

    for (int c = 0; c < nChunks; ++c) {
        int row0 = c * chunkRows;
        // LN1 + modulate + shift + window partition: x[row0..] -> slotS (winC)
        ln_kernel<1><<<dim3(chunkRows / 4), dim3(256), 0, stream>>>(
            x, mod, slotS, 0, 512, row0);
        // qkv GEMM: winC @ wT_qkv -> slotL (qkvC)
        gemm128<0><<<dim3(chunkRows / 128, 12), dim3(256), 0, stream>>>(
            slotS, wT_qkv, qkv_b, slotL, nullptr, mod, 1536, 512, 0);
        // attention (MFMA): qkvC -> slotS (aoC; winC is dead)
        attn_mfma<<<dim3(CB * 64, 4), dim3(256), 0, stream>>>(slotL, relb, slotS);
        // proj + window reverse + unshift + residual(x) -> d_out (x2, fp32)
        gemm128<2><<<dim3(chunkRows / 128, 4), dim3(256), 0, stream>>>(
            slotS, wT_proj, proj_b, outp, x, mod, 512, 512, row0);
        // LN2 + modulate: d_out[row0..] -> slotS (h2C; aoC is dead)
        ln_kernel<0><<<dim3(chunkRows / 4), dim3(256), 0, stream>>>(
            outp, mod, slotS, 1536, 2048, row0);
        // FF1 + GELU: h2C -> slotL (ffiC; qkvC is dead)
        gemm128<1><<<dim3(chunkRows / 128, 16), dim3(256), 0, stream>>>(
            slotS, wT_ff1, ff_b1, slotL, nullptr, mod, 2048, 512, 0);
        // FF2 + residual(x2) -> d_out
        gemm128<3><<<dim3(chunkRows / 128, 4), dim3(256), 0, stream>>>(
            slotL, wT_ff2, ff_b2, outp, outp, mod, 512, 2048, row0);
    }
}

// Round 4
// 1072.272 us; speedup vs baseline: 1.0807x; 1.0807x over previous
//
#include <hip/hip_runtime.h>
#include <cmath>

typedef unsigned short u16;
typedef unsigned short u16x2 __attribute__((ext_vector_type(2)));
typedef unsigned short u16x4 __attribute__((ext_vector_type(4)));
typedef unsigned short u16x8 __attribute__((ext_vector_type(8)));
typedef short s16x8 __attribute__((ext_vector_type(8)));
typedef float f32x4 __attribute__((ext_vector_type(4)));
typedef float f32x2 __attribute__((ext_vector_type(2)));

#define B_SZ 16
#define HW 56
#define L_TOK 3136      // 56*56
#define C_DIM 512
#define NHEAD 16
#define DHEAD 32
#define WS7 7
#define NWIN 49
#define ROWS_TOTAL 50176   // 16*3136
#define MLP_DIM 2048

__device__ __forceinline__ float bf2f(u16 u) {
    union { unsigned int i; float f; } z;
    z.i = ((unsigned int)u) << 16;
    return z.f;
}
__device__ __forceinline__ u16 f2bf(float f) {
    union { float f; unsigned int i; } z;
    z.f = f;
    unsigned int r = z.i + 0x7fffu + ((z.i >> 16) & 1u);
    return (u16)(r >> 16);
}

// async global->LDS, 16B per lane; LDS dest = wave-uniform base + lane*16
__device__ __forceinline__ void gl_lds16(const u16* g, u16* l) {
    __builtin_amdgcn_global_load_lds(
        (const __attribute__((address_space(1))) unsigned int*)g,
        (__attribute__((address_space(3))) unsigned int*)l,
        16, 0, 0);
}

// ---------------------------------------------------------------------------
// 1) mod = silu(emb) @ adaLN_w + adaLN_b -> fp32 [16,3072]
// ---------------------------------------------------------------------------
__global__ __launch_bounds__(256)
void mod_kernel(const float* __restrict__ emb, const float* __restrict__ w,
                const float* __restrict__ bias, float* __restrict__ mod)
{
    int b = blockIdx.y;
    int o = blockIdx.x * 256 + threadIdx.x;
    __shared__ float se[512];
    for (int i = threadIdx.x; i < 512; i += 256) {
        float e = emb[b * 512 + i];
        se[i] = e / (1.0f + expf(-e));
    }
    __syncthreads();
    float acc = bias[o];
    #pragma unroll 8
    for (int k = 0; k < 512; ++k)
        acc += se[k] * w[(size_t)k * 3072 + o];
    mod[b * 3072 + o] = acc;
}

// ---------------------------------------------------------------------------
// 2) weight transpose + bf16 cast: Wt[n][k] = bf16(W[k][n])
// ---------------------------------------------------------------------------
__global__ __launch_bounds__(1024)
void transpose_kernel(const float* __restrict__ W, u16* __restrict__ Wt, int K, int N)
{
    __shared__ float tile[32][33];
    int k0 = blockIdx.x * 32, n0 = blockIdx.y * 32;
    tile[threadIdx.y][threadIdx.x] = W[(size_t)(k0 + threadIdx.y) * N + (n0 + threadIdx.x)];
    __syncthreads();
    Wt[(size_t)(n0 + threadIdx.y) * K + (k0 + threadIdx.x)] = f2bf(tile[threadIdx.x][threadIdx.y]);
}

// ---------------------------------------------------------------------------
// 3) LN + adaLN modulate; wave-per-row (4 rows/block), no LDS / syncthreads.
// ---------------------------------------------------------------------------
template<int WINDOWED>
__global__ __launch_bounds__(256)
void ln_kernel(const float* __restrict__ xin, const float* __restrict__ mod,
               u16* __restrict__ out, int shOff, int scOff, int rowBase)
{
    int wv   = threadIdx.x >> 6;
    int lane = threadIdx.x & 63;
    int rbl = blockIdx.x * 4 + wv;        // chunk-local row
    int rb  = rbl + rowBase;              // global sequence row
    int b = rb / L_TOK, l = rb - b * L_TOK;
    const float* xr = xin + (size_t)rb * C_DIM;
    int c0 = lane * 8;
    f32x4 u0 = *(const f32x4*)(xr + c0);
    f32x4 u1 = *(const f32x4*)(xr + c0 + 4);
    float s = u0.x + u0.y + u0.z + u0.w + u1.x + u1.y + u1.z + u1.w;
    float q = u0.x*u0.x + u0.y*u0.y + u0.z*u0.z + u0.w*u0.w
            + u1.x*u1.x + u1.y*u1.y + u1.z*u1.z + u1.w*u1.w;
    #pragma unroll
    for (int off = 32; off > 0; off >>= 1) {
        s += __shfl_xor(s, off);
        q += __shfl_xor(q, off);
    }
    float mu = s * (1.0f / 512.0f);
    float var = q * (1.0f / 512.0f) - mu * mu;
    float rstd = rsqrtf(var + 1e-6f);
    const float* mb = mod + b * 3072;
    f32x4 sc0 = *(const f32x4*)(mb + scOff + c0);
    f32x4 sc1 = *(const f32x4*)(mb + scOff + c0 + 4);
    f32x4 sh0 = *(const f32x4*)(mb + shOff + c0);
    f32x4 sh1 = *(const f32x4*)(mb + shOff + c0 + 4);
    float y[8];
    y[0] = (u0.x - mu) * rstd * (1.0f + sc0.x) + sh0.x;
    y[1] = (u0.y - mu) * rstd * (1.0f + sc0.y) + sh0.y;
    y[2] = (u0.z - mu) * rstd * (1.0f + sc0.z) + sh0.z;
    y[3] = (u0.w - mu) * rstd * (1.0f + sc0.w) + sh0.w;
    y[4] = (u1.x - mu) * rstd * (1.0f + sc1.x) + sh1.x;
    y[5] = (u1.y - mu) * rstd * (1.0f + sc1.y) + sh1.y;
    y[6] = (u1.z - mu) * rstd * (1.0f + sc1.z) + sh1.z;
    y[7] = (u1.w - mu) * rstd * (1.0f + sc1.w) + sh1.w;
    size_t drow;
    if (WINDOWED) {
        int hh = l / HW, ww = l - hh * HW;
        int hs = hh - 3; if (hs < 0) hs += HW;
        int ws2 = ww - 3; if (ws2 < 0) ws2 += HW;
        int wi = (hs / WS7) * 8 + (ws2 / WS7);
        int n  = (hs % WS7) * WS7 + (ws2 % WS7);
        int b_local = rbl / L_TOK;
        drow = (size_t)((b_local * 64 + wi) * NWIN + n);
    } else {
        drow = (size_t)rbl;
    }
    u16x8 o;
    #pragma unroll
    for (int i = 0; i < 8; ++i) o[i] = f2bf(y[i]);
    *(u16x8*)(out + drow * C_DIM + c0) = o;
}

// ---------------------------------------------------------------------------
// 4) GEMM: C[M,N] = A[M,K] @ Bt[N,K]^T + bias
//    128x128 tile, BK=32, 4 waves x (4x4) mfma_f32_16x16x32_bf16.
//    T3-minimum 2-phase: static double-buffer (32 KB LDS), STAGE(t+1) issued
//    BEFORE compute(t), single vmcnt(0)+lgkmcnt(0) + raw barrier per K-step.
//    1-D grid, bijective XCD-chunked decode, col-block-fastest within chunk:
//    each XCD's L2 keeps one A-tile + the whole weight panel resident.
// ---------------------------------------------------------------------------
template<int EPI>
__global__ __launch_bounds__(256)
void gemm128(const u16* __restrict__ A, const u16* __restrict__ Bt,
             const float* __restrict__ bias, void* __restrict__ outv,
             const float* __restrict__ resid, const float* __restrict__ mod,
             int N, int K, int rowOffset, int nyb)
{
    __shared__ u16 sA[2][128][32];   // 16 KB
    __shared__ u16 sB[2][128][32];   // 16 KB
    const int tid  = threadIdx.x;
    const int lane = tid & 63;
    const int wave = tid >> 6;
    const int wr = (wave >> 1) * 64;
    const int wc = (wave & 1) * 64;
    const int quad = lane >> 4;
    const int mrow = lane & 15;

    // bijective XCD-chunked swizzle (m204), col-block fastest within chunk
    const int nwg  = gridDim.x;
    const int orig = blockIdx.x;
    const int xq = nwg >> 3, xr = nwg & 7;
    const int xcd = orig & 7, xidx = orig >> 3;
    const int wgid = (xcd < xr ? xcd * (xq + 1)
                               : xr * (xq + 1) + (xcd - xr) * xq) + xidx;
    const int bx = wgid / nyb;
    const int by = wgid - bx * nyb;
    const int rowBase = bx * 128;
    const int colBase = by * 128;

    const int r0   = wave * 32;
    const int lrow = lane >> 2;
    const int lcol = (lane & 3) * 8;          // u16 offset in row
    const u16* gA = A  + (size_t)(rowBase + r0 + lrow) * K + lcol;
    const u16* gB = Bt + (size_t)(colBase + r0 + lrow) * K + lcol;
    const size_t gstep = (size_t)16 * K;

    f32x4 acc[4][4] = {};
    const int nt = K >> 5;

#define STAGE(bi, kk) do {                                 \
    gl_lds16(gA + (kk),         &sA[bi][r0][0]);           \
    gl_lds16(gA + (kk) + gstep, &sA[bi][r0 + 16][0]);      \
    gl_lds16(gB + (kk),         &sB[bi][r0][0]);           \
    gl_lds16(gB + (kk) + gstep, &sB[bi][r0 + 16][0]);      \
} while (0)

    STAGE(0, 0);
    asm volatile("s_waitcnt vmcnt(0)" ::: "memory");
    __builtin_amdgcn_s_barrier();

    for (int t = 0; t < nt; ++t) {
        const int cur = t & 1;
        if (t + 1 < nt) STAGE(cur ^ 1, (t + 1) << 5);   // prefetch in flight
        s16x8 af[4], bg[4];
        #pragma unroll
        for (int tt = 0; tt < 4; ++tt) {
            af[tt] = *(const s16x8*)&sA[cur][wr + tt * 16 + mrow][quad * 8];
            bg[tt] = *(const s16x8*)&sB[cur][wc + tt * 16 + mrow][quad * 8];
        }
        #pragma unroll
        for (int tm = 0; tm < 4; ++tm)
            #pragma unroll
            for (int tn = 0; tn < 4; ++tn)
                acc[tm][tn] = __builtin_amdgcn_mfma_f32_16x16x32_bf16(
                    af[tm], bg[tn], acc[tm][tn], 0, 0, 0);
        if (t + 1 < nt) {
            // prefetch was issued ~compute-phase earlier: latency mostly hidden
            asm volatile("s_waitcnt vmcnt(0) lgkmcnt(0)" ::: "memory");
            __builtin_amdgcn_s_barrier();
        }
    }
#undef STAGE

    #pragma unroll
    for (int tm = 0; tm < 4; ++tm) {
        #pragma unroll
        for (int tn = 0; tn < 4; ++tn) {
            int col = colBase + wc + tn * 16 + mrow;
            float bv = bias[col];
            #pragma unroll
            for (int i = 0; i < 4; ++i) {
                int r = rowBase + wr + tm * 16 + quad * 4 + i;   // chunk-local
                float v = acc[tm][tn][i] + bv;
                if constexpr (EPI == 0) {
                    ((u16*)outv)[(size_t)r * N + col] = f2bf(v);
                } else if constexpr (EPI == 1) {
                    float g = 0.5f * v * (1.0f + erff(v * 0.70710678118654752f));
                    ((u16*)outv)[(size_t)r * N + col] = f2bf(g);
                } else if constexpr (EPI == 2) {
                    int rg = r + rowOffset;        // global window-layout row
                    int b = rg / L_TOK;
                    int rem = rg - b * L_TOK;
                    int wi = rem / NWIN;
                    int n  = rem - wi * NWIN;
                    int hs  = (wi >> 3) * WS7 + n / WS7;
                    int ws2 = (wi & 7) * WS7 + n % WS7;
                    int hh = hs + 3;  if (hh >= HW)  hh -= HW;
                    int ww = ws2 + 3; if (ww >= HW)  ww -= HW;
                    size_t dst = ((size_t)(b * L_TOK + hh * HW + ww)) * C_DIM + col;
                    float g = mod[b * 3072 + 1024 + col];
                    ((float*)outv)[dst] = resid[dst] + g * v;
                } else {  // EPI == 3
                    int rg = r + rowOffset;        // global sequence row
                    int b = rg / L_TOK;
                    size_t dst = (size_t)rg * C_DIM + col;
                    float g = mod[b * 3072 + 2560 + col];
                    ((float*)outv)[dst] = resid[dst] + g * v;
                }
            }
        }
    }
}

// ---------------------------------------------------------------------------
// 5) MFMA windowed attention. Block = 4 waves = 4 heads of one window.
// ---------------------------------------------------------------------------
__global__ __launch_bounds__(256)
void attn_mfma(const u16* __restrict__ qkv, const float* __restrict__ bias_table,
               u16* __restrict__ out)
{
    const int w    = blockIdx.x;          // chunk-local: b_local*64 + wi
    const int hg   = blockIdx.y;          // 0..3
    const int wave = threadIdx.x >> 6;
    const int lane = threadIdx.x & 63;
    const int h    = hg * 4 + wave;
    const int wi   = w & 63;
    const int quad = lane >> 4;
    const int mrow = lane & 15;

    __shared__ u16 sP[4][64][72];      // per-wave P (bf16), pitch 72 (144B rows)
    __shared__ u16 sVt[4][32][72];     // per-wave V^T (bf16)
    __shared__ float sBias[4][169];    // per-wave head bias slice

    const u16* qb = qkv + (size_t)w * NWIN * 1536 + h * DHEAD;

    // stage per-head bias slice (strided global, L2-resident table)
    for (int e = lane; e < 169; e += 64)
        sBias[wave][e] = bias_table[e * NHEAD + h];

    // stage V transposed: rows 0..48 real, 49..63 zeroed
    #pragma unroll
    for (int rr = 0; rr < 4; ++rr) {
        int e = rr * 64 + lane;
        int r = e >> 2, d0 = (e & 3) * 8;
        u16x8 vv = {};
        if (e < 196)
            vv = *(const u16x8*)(qb + (size_t)r * 1536 + 1024 + d0);
        #pragma unroll
        for (int j = 0; j < 8; ++j)
            sVt[wave][d0 + j][r] = vv[j];
    }

    // Q/K fragments direct from global; pad rows (49..63) clamped to 48
    s16x8 qf[4], kf[4];
    #pragma unroll
    for (int t = 0; t < 4; ++t) {
        int r = t * 16 + mrow; if (r > 48) r = 48;
        qf[t] = *(const s16x8*)(qb + (size_t)r * 1536 + quad * 8);
        kf[t] = *(const s16x8*)(qb + (size_t)r * 1536 + 512 + quad * 8);
    }
    __syncthreads();   // sVt / sBias visible

    // S = Q K^T : S[m][n], m = tm*16+quad*4+i, n = tn*16+mrow
    f32x4 sacc[4][4] = {};
    #pragma unroll
    for (int tm = 0; tm < 4; ++tm)
        #pragma unroll
        for (int tn = 0; tn < 4; ++tn)
            sacc[tm][tn] = __builtin_amdgcn_mfma_f32_16x16x32_bf16(
                qf[tm], kf[tn], sacc[tm][tn], 0, 0, 0);

    const float scale = 0.17677669529663687f;   // 1/sqrt(32)
    const int wh = wi >> 3, ww = wi & 7;

    // per-lane key-side terms (constant across tm,i)
    int khA[4], kwA[4], rkA[4], nOK[4];
    #pragma unroll
    for (int tn = 0; tn < 4; ++tn) {
        int n = tn * 16 + mrow;
        nOK[tn] = (n < NWIN);
        int nc = n > 48 ? 48 : n;
        khA[tn] = nc / 7; kwA[tn] = nc - khA[tn] * 7;
        int gkh = wh * 7 + khA[tn], gkw = ww * 7 + kwA[tn];
        rkA[tn] = (gkh < 49 ? 0 : (gkh < 53 ? 1 : 2)) * 3
                + (gkw < 49 ? 0 : (gkw < 53 ? 1 : 2));
    }

    #pragma unroll
    for (int tm = 0; tm < 4; ++tm) {
        #pragma unroll
        for (int i = 0; i < 4; ++i) {
            int m = tm * 16 + quad * 4 + i;
            int mc = m > 48 ? 48 : m;            // garbage rows: keep idx bounded
            int qh = mc / 7, qw = mc - qh * 7;
            int gqh = wh * 7 + qh, gqw = ww * 7 + qw;
            int rq = (gqh < 49 ? 0 : (gqh < 53 ? 1 : 2)) * 3
                   + (gqw < 49 ? 0 : (gqw < 53 ? 1 : 2));
            float v[4];
            #pragma unroll
            for (int tn = 0; tn < 4; ++tn) {
                float s = sacc[tm][tn][i] * scale;
                s += sBias[wave][(qh - khA[tn] + 6) * 13 + (qw - kwA[tn] + 6)];
                if (rq != rkA[tn]) s -= 100.0f;
                v[tn] = nOK[tn] ? s : -1e30f;
            }
            float mx = fmaxf(fmaxf(v[0], v[1]), fmaxf(v[2], v[3]));
            mx = fmaxf(mx, __shfl_xor(mx, 1));
            mx = fmaxf(mx, __shfl_xor(mx, 2));
            mx = fmaxf(mx, __shfl_xor(mx, 4));
            mx = fmaxf(mx, __shfl_xor(mx, 8));
            float p0 = __expf(v[0] - mx), p1 = __expf(v[1] - mx);
            float p2 = __expf(v[2] - mx), p3 = __expf(v[3] - mx);
            float sum = p0 + p1 + p2 + p3;
            sum += __shfl_xor(sum, 1);
            sum += __shfl_xor(sum, 2);
            sum += __shfl_xor(sum, 4);
            sum += __shfl_xor(sum, 8);
            float inv = 1.0f / sum;
            float pp[4] = { p0 * inv, p1 * inv, p2 * inv, p3 * inv };
            // pack (n, n+1) bf16 pairs via neighbor shfl; even-mrow lanes write
            #pragma unroll
            for (int tn = 0; tn < 4; ++tn) {
                float po = __shfl_xor(pp[tn], 1);
                if (!(mrow & 1)) {
                    unsigned int pk = (unsigned int)f2bf(pp[tn])
                                    | ((unsigned int)f2bf(po) << 16);
                    *(unsigned int*)&sP[wave][m][tn * 16 + mrow] = pk;
                }
            }
        }
    }
    __syncthreads();   // sP ready

    // O^T[d][m] = sum_n V[n][d] * P[m][n] ; A = V^T frags, B = P frags
    f32x4 oacc[2][4] = {};
    #pragma unroll
    for (int ks = 0; ks < 2; ++ks) {
        s16x8 vf[2], pf[4];
        #pragma unroll
        for (int td = 0; td < 2; ++td)
            vf[td] = *(const s16x8*)&sVt[wave][td * 16 + mrow][ks * 32 + quad * 8];
        #pragma unroll
        for (int tm = 0; tm < 4; ++tm)
            pf[tm] = *(const s16x8*)&sP[wave][tm * 16 + mrow][ks * 32 + quad * 8];
        #pragma unroll
        for (int td = 0; td < 2; ++td)
            #pragma unroll
            for (int tm = 0; tm < 4; ++tm)
                oacc[td][tm] = __builtin_amdgcn_mfma_f32_16x16x32_bf16(
                    vf[td], pf[tm], oacc[td][tm], 0, 0, 0);
    }

    // store: lane holds O^T[d = td*16+quad*4+i][m = tm*16+mrow]
    #pragma unroll
    for (int tm = 0; tm < 4; ++tm) {
        int m = tm * 16 + mrow;
        if (m < NWIN) {
            u16* orow = out + ((size_t)(w * NWIN + m)) * C_DIM + h * DHEAD;
            #pragma unroll
            for (int td = 0; td < 2; ++td) {
                u16x4 ov;
                #pragma unroll
                for (int i = 0; i < 4; ++i) ov[i] = f2bf(oacc[td][tm][i]);
                *(u16x4*)(orow + td * 16 + quad * 4) = ov;
            }
        }
    }
}

// ---------------------------------------------------------------------------
// fp32 I/O, bf16 compute core. x2 lives in d_out.
// Workspace: two aliased slots (lifetimes disjoint):
//   slotS = winC -> aoC -> h2C   (CB * 3136 * 512  * 2B per batch)
//   slotL = qkvC -> ffiC         (CB * 3136 * 2048 * 2B per batch)
// CB tiers: 4 (70.7 MB, proven) / 8 (134.9 MB) / 16 (263.4 MB, single chunk).
// ---------------------------------------------------------------------------
extern "C" void kernel_launch(void* const* d_in, const int* in_sizes, int n_in,
                              void* d_out, int out_size, void* d_ws, size_t ws_size,
                              hipStream_t stream)
{
    const float* x       = (const float*)d_in[0];
    const float* emb     = (const float*)d_in[1];
    const float* adaLN_w = (const float*)d_in[2];
    const float* adaLN_b = (const float*)d_in[3];
    const float* qkv_w   = (const float*)d_in[4];
    const float* qkv_b   = (const float*)d_in[5];
    const float* proj_w  = (const float*)d_in[6];
    const float* proj_b  = (const float*)d_in[7];
    const float* relb    = (const float*)d_in[8];
    const float* ff_w1   = (const float*)d_in[9];
    const float* ff_b1   = (const float*)d_in[10];
    const float* ff_w2   = (const float*)d_in[11];
    const float* ff_b2   = (const float*)d_in[12];
    float* outp = (float*)d_out;

    char* ws = (char*)d_ws;
    float* mod   = (float*)(ws + 0);                  //    196,608 B
    u16* wT_qkv  = (u16*)(ws + 196608);               //  1,572,864 B
    u16* wT_proj = (u16*)(ws + 1769472);              //    524,288 B
    u16* wT_ff1  = (u16*)(ws + 2293760);              //  2,097,152 B
    u16* wT_ff2  = (u16*)(ws + 4390912);              //  2,097,152 B
    char* slots  = ws + 6488064;

    const size_t perB_S = (size_t)L_TOK * C_DIM * sizeof(u16);   //  3,211,264
    const size_t perB_L = (size_t)L_TOK * MLP_DIM * sizeof(u16); // 12,845,056

    int CB = 4;   // 70,713,344 B total (proven fit)
    if (ws_size >= 6488064 + 8  * (perB_S + perB_L)) CB = 8;
    if (ws_size >= 6488064 + 16 * (perB_S + perB_L)) CB = 16;

    const int nChunks   = B_SZ / CB;
    const int chunkRows = CB * L_TOK;
    const int nrb       = chunkRows / 128;            // row-blocks per chunk
    u16* slotS = (u16*)slots;                         // winC / aoC / h2C
    u16* slotL = (u16*)(slots + (size_t)CB * perB_S); // qkvC / ffiC

    // prolog (once)
    mod_kernel<<<dim3(12, 16), dim3(256), 0, stream>>>(emb, adaLN_w, adaLN_b, mod);
    transpose_kernel<<<dim3(16, 48), dim3(32, 32), 0, stream>>>(qkv_w,  wT_qkv, 512, 1536);
    transpose_kernel<<<dim3(16, 16), dim3(32, 32), 0, stream>>>(proj_w, wT_proj, 512, 512);
    transpose_kernel<<<dim3(16, 64), dim3(32, 32), 0, stream>>>(ff_w1,  wT_ff1, 512, 2048);
    transpose_kernel<<<dim3(64, 16), dim3(32, 32), 0, stream>>>(ff_w2,  wT_ff2, 2048, 512);

    for (int c = 0; c < nChunks; ++c) {
        int row0 = c * chunkRows;
        // LN1 + modulate + shift + window partition: x[row0..] -> slotS (winC)
        ln_kernel<1><<<dim3(chunkRows / 4), dim3(256), 0, stream>>>(
            x, mod, slotS, 0, 512, row0);
        // qkv GEMM: winC @ wT_qkv -> slotL (qkvC)
        gemm128<0><<<dim3(nrb * 12), dim3(256), 0, stream>>>(
            slotS, wT_qkv, qkv_b, slotL, nullptr, mod, 1536, 512, 0, 12);
        // attention (MFMA): qkvC -> slotS (aoC; winC is dead)
        attn_mfma<<<dim3(CB * 64, 4), dim3(256), 0, stream>>>(slotL, relb, slotS);
        // proj + window reverse + unshift + residual(x) -> d_out (x2, fp32)
        gemm128<2><<<dim3(nrb * 4), dim3(256), 0, stream>>>(
            slotS, wT_proj, proj_b, outp, x, mod, 512, 512, row0, 4);
        // LN2 + modulate: d_out[row0..] -> slotS (h2C; aoC is dead)
        ln_kernel<0><<<dim3(chunkRows / 4), dim3(256), 0, stream>>>(
            outp, mod, slotS, 1536, 2048, row0);
        // FF1 + GELU: h2C -> slotL (ffiC; qkvC is dead)
        gemm128<1><<<dim3(nrb * 16), dim3(256), 0, stream>>>(
            slotS, wT_ff1, ff_b1, slotL, nullptr, mod, 2048, 512, 0, 16);
        // FF2 + residual(x2) -> d_out
        gemm128<3><<<dim3(nrb * 4), dim3(256), 0, stream>>>(
            slotL, wT_ff2, ff_b2, outp, outp, mod, 512, 2048, row0, 4);
    }
}